// Round 12
// baseline (2096.371 us; speedup 1.0000x reference)
//
#include <hip/hip_runtime.h>
#include <hip/hip_bf16.h>

// Problem constants
#define N_TOK   576
#define MPAD    640            // padded to 5*128
#define DIM     1024
#define VOCAB   262400
#define BM      128
#define BN      128
#define BK      128            // k-elements per step (fp8: 128 B rows)
#define NT      (DIM/BK)       // 8 K-steps
#define RB      5              // MPAD/BM row blocks
#define VBLKS   (VOCAB/BN)     // 2050
#define NWG     (RB*VBLKS)     // 10250
#define IGNORE_INDEX (-100)
#define SCALE1  0x7F7F7F7F     // e8m0 = 127 -> 1.0 in every byte

typedef float f32x4 __attribute__((ext_vector_type(4)));
typedef int   i32x8 __attribute__((ext_vector_type(8)));

#define AS1 __attribute__((address_space(1)))
#define AS3 __attribute__((address_space(3)))

__device__ __forceinline__ int cvt4_fp8(float4 v) {
  int r = __builtin_amdgcn_cvt_pk_fp8_f32(v.x, v.y, 0, false);   // bytes 0,1
  r     = __builtin_amdgcn_cvt_pk_fp8_f32(v.z, v.w, r, true);    // bytes 2,3
  return r;
}

// ---------- kernel 1: fused prep (x->fp8 cvt  +  exact target logits) -----
__global__ void k_prep(const float* __restrict__ x, const float* __restrict__ W,
                       const int* __restrict__ labels,
                       unsigned char* __restrict__ xq, float* __restrict__ tgt) {
  if (blockIdx.x < MPAD * DIM / 2048) {     // ---- cvt part: 320 blocks ----
    int idx = blockIdx.x * 256 + threadIdx.x;
    long e0 = (long)idx * 8;
    int row = (int)(e0 >> 10);
    uint2 o;
    if (row < N_TOK) {
      float4 a = *(const float4*)(x + e0);
      float4 b = *(const float4*)(x + e0 + 4);
      o.x = (unsigned)cvt4_fp8(a);
      o.y = (unsigned)cvt4_fp8(b);
    } else { o.x = o.y = 0u; }
    *(uint2*)(xq + e0) = o;
  } else {                                  // ---- tgt part: 576 blocks ----
    int n = blockIdx.x - MPAD * DIM / 2048;
    int lab = labels[n];
    int t = threadIdx.x;
    float s = 0.0f;
    if (lab >= 0) {
      const float4 a = ((const float4*)(x + (size_t)n * DIM))[t];
      const float4 b = ((const float4*)(W + (size_t)lab * DIM))[t];
      s = a.x*b.x + a.y*b.y + a.z*b.z + a.w*b.w;
    }
    #pragma unroll
    for (int off = 32; off >= 1; off >>= 1) s += __shfl_xor(s, off);
    __shared__ float wsum[4];
    if ((t & 63) == 0) wsum[t >> 6] = s;
    __syncthreads();
    if (t == 0) {
      float d = wsum[0] + wsum[1] + wsum[2] + wsum[3];
      tgt[n] = (lab >= 0) ? 30.0f * tanhf(d * (1.0f / 30.0f)) : 0.0f;
    }
  }
}

// ---------- kernel 2: MX-scaled fp8 GEMM (scale=1.0) + softcap-exp-sum ----
// R9 skeleton at BK=128: fp8 rows are 128B -> R2's plain chunk swizzle
// (16B chunk j of row r at slot j^(r&7); 8 lanes/row-group cover all 8
// slots -> conflict-free). A via global_load_lds (linear dest, source
// pre-swizzled); B reg-staged fp32 -> cvt_pk_fp8 -> ds_write_b128.
// MFMA: mfma_scale_f32_16x16x128_f8f6f4 with scale=1.0 (0x7F e8m0) --
// numerically identical to plain fp8, 2x the matrix rate, 4x K per inst.
// Lane (l15,lh) holds k-bytes lh*32..+31 = global chunks {2lh,2lh+1};
// identical slot mapping for A and B (+ uniform scales) makes the result
// independent of the HW slot->k permutation. C/D layout shape-determined
// (m121-128): col=l15, row=lh*4+j -- same epilogue as R7-R11.
__global__ __launch_bounds__(256, 3) void k_gemm(
    const float* __restrict__ W,            // [VOCAB][DIM] fp32
    const unsigned char* __restrict__ Xq,   // [MPAD][DIM] fp8
    float* __restrict__ S)                  // [MPAD] running sum of exp(z-30)
{
  __shared__ unsigned char Asl[BM * BK];    // 16 KB
  __shared__ unsigned char Bsl[BN * BK];    // 16 KB

  // ---- bijective XCD swizzle (m204), rb-fastest logical order ----
  const int q  = NWG / 8, rm = NWG % 8;     // 1281, 2
  const int orig = blockIdx.x;
  const int xcd  = orig & 7;
  const int part = orig >> 3;
  const int bid  = (xcd < rm ? xcd * (q + 1) : rm * (q + 1) + (xcd - rm) * q) + part;

  const int rb  = bid % RB;
  const int vb  = bid / RB;
  const int m0  = rb * BM;
  const long n0 = (long)vb * BN;

  const int t   = threadIdx.x;
  const int l   = t & 63;
  const int w   = t >> 6;
  const int wm  = w >> 1, wn = w & 1;       // 2x2 waves, 64x64 per wave
  const int l15 = l & 15, lh = l >> 4;
  const int e8  = l15 & 7;

  // ---- staging geometry: 4 x 16B chunks/thread/operand ----
  // chunk lin: r = lin>>3 (row), j = lin&7; LDS slot = j^(r&7).
  const unsigned char* asrc[4];             // A source pre-swizzled
  const float* bsrc[4];                     // B source linear (cvt then
  int bdst[4];                              //   write to swizzled slot)
  #pragma unroll
  for (int i = 0; i < 4; ++i) {
    int lin = t + i * 256;                  // 0..1023
    int r   = lin >> 3;
    int j   = lin & 7;
    asrc[i] = Xq + (size_t)(m0 + r) * DIM + (j ^ (r & 7)) * 16;
    bsrc[i] = W + (n0 + r) * DIM + j * 16;  // 16 fp32 = one 16B fp8 chunk
    bdst[i] = r * BK + (j ^ (r & 7)) * 16;
  }
  // ---- frag read offsets: chunks {2lh, 2lh+1} swizzled ----
  const int fo0 = ((2 * lh)     ^ e8) * 16;
  const int fo1 = ((2 * lh + 1) ^ e8) * 16;

  f32x4 acc[4][4];
  const f32x4 zero4 = {0.0f, 0.0f, 0.0f, 0.0f};
  #pragma unroll
  for (int i = 0; i < 4; ++i)
    #pragma unroll
    for (int j = 0; j < 4; ++j) acc[i][j] = zero4;

  for (int k0 = 0; k0 < DIM; k0 += BK) {
    // -- B global loads (4 chunks x 4 float4) issued before the barrier --
    float4 fb[4][4];
    #pragma unroll
    for (int i = 0; i < 4; ++i)
      #pragma unroll
      for (int c = 0; c < 4; ++c)
        fb[i][c] = *(const float4*)(bsrc[i] + k0 + c * 4);

    __syncthreads();                        // prev-iter frag reads done

    // -- A: 4 x 16B direct global->LDS (linear dest) --
    #pragma unroll
    for (int i = 0; i < 4; ++i)
      __builtin_amdgcn_global_load_lds((const AS1 void*)(asrc[i] + k0),
          (AS3 void*)(Asl + (t + i * 256) * 16), 16, 0, 0);
    // -- B: cvt 16 fp32 -> 16 fp8 per chunk, one ds_write_b128 each --
    #pragma unroll
    for (int i = 0; i < 4; ++i) {
      uint4 o;
      o.x = (unsigned)cvt4_fp8(fb[i][0]);
      o.y = (unsigned)cvt4_fp8(fb[i][1]);
      o.z = (unsigned)cvt4_fp8(fb[i][2]);
      o.w = (unsigned)cvt4_fp8(fb[i][3]);
      *(uint4*)(Bsl + bdst[i]) = o;
    }
    __syncthreads();                        // tiles ready (vmcnt+lgkm drained)

    // -- A frags: 4 rows x 32B (2 x b128) --
    i32x8 af[4];
    #pragma unroll
    for (int mi = 0; mi < 4; ++mi) {
      const unsigned char* base = Asl + (wm * 64 + mi * 16 + l15) * BK;
      union { uint4 u[2]; i32x8 v; } c_;
      c_.u[0] = *(const uint4*)(base + fo0);
      c_.u[1] = *(const uint4*)(base + fo1);
      af[mi] = c_.v;
    }
    // -- B frags one at a time (keeps VGPR pressure down) + 4 MFMA each --
    __builtin_amdgcn_s_setprio(1);
    #pragma unroll
    for (int ni = 0; ni < 4; ++ni) {
      const unsigned char* base = Bsl + (wn * 64 + ni * 16 + l15) * BK;
      union { uint4 u[2]; i32x8 v; } c_;
      c_.u[0] = *(const uint4*)(base + fo0);
      c_.u[1] = *(const uint4*)(base + fo1);
      #pragma unroll
      for (int mi = 0; mi < 4; ++mi)
        acc[mi][ni] = __builtin_amdgcn_mfma_scale_f32_16x16x128_f8f6f4(
            af[mi], c_.v, acc[mi][ni],
            0, 0,                           // cbsz=fp8, blgp=fp8
            0, SCALE1,                      // opsel_a, scale_a = 1.0
            0, SCALE1);                     // opsel_b, scale_b = 1.0
    }
    __builtin_amdgcn_s_setprio(0);
  }

  // ---- epilogue: p = exp(z-30) = exp(-60/(exp(g/15)+1)); row sums; atomics
  // C frag layout (shape-determined): col = l15 (vocab), row = lh*4 + j
  #pragma unroll
  for (int mi = 0; mi < 4; ++mi) {
    #pragma unroll
    for (int j = 0; j < 4; ++j) {
      float s = 0.0f;
      #pragma unroll
      for (int ni = 0; ni < 4; ++ni) {
        float g   = acc[mi][ni][j];
        float tp1 = __expf(g * (1.0f / 15.0f)) + 1.0f;
        s += __expf(-60.0f * __builtin_amdgcn_rcpf(tp1));
      }
      s += __shfl_xor(s, 1);
      s += __shfl_xor(s, 2);
      s += __shfl_xor(s, 4);
      s += __shfl_xor(s, 8);
      if (l15 == 0) {
        int row = m0 + wm * 64 + mi * 16 + lh * 4 + j;
        atomicAdd(&S[row], s);              // padded rows land in S[576..640)
      }
    }
  }
}

// ---------- kernel 3: final reduce -> loss ----------
__global__ void k_final(const float* __restrict__ S, const float* __restrict__ tgt,
                        const int* __restrict__ labels, float* __restrict__ out) {
  int t = threadIdx.x;
  float sum = 0.0f, cnt = 0.0f;
  for (int n = t; n < N_TOK; n += 256) {
    if (labels[n] != IGNORE_INDEX) {
      sum += 30.0f + __logf(S[n]) - tgt[n];  // lse = 30 + log(sum exp(z-30))
      cnt += 1.0f;
    }
  }
  #pragma unroll
  for (int off = 32; off >= 1; off >>= 1) {
    sum += __shfl_xor(sum, off);
    cnt += __shfl_xor(cnt, off);
  }
  __shared__ float as_[4], ac_[4];
  if ((t & 63) == 0) { as_[t >> 6] = sum; ac_[t >> 6] = cnt; }
  __syncthreads();
  if (t == 0) out[0] = (as_[0]+as_[1]+as_[2]+as_[3]) / (ac_[0]+ac_[1]+ac_[2]+ac_[3]);
}

extern "C" void kernel_launch(void* const* d_in, const int* in_sizes, int n_in,
                              void* d_out, int out_size, void* d_ws, size_t ws_size,
                              hipStream_t stream) {
  const float* x      = (const float*)d_in[0];
  const float* W      = (const float*)d_in[1];
  const int*   labels = (const int*)d_in[2];
  float* out = (float*)d_out;

  // ws layout: xq [640*1024 fp8] | S [640 f32] | tgt [576 f32]  (~0.66 MB)
  char* ws = (char*)d_ws;
  unsigned char* xq = (unsigned char*)ws;
  float* S   = (float*)(ws + (size_t)MPAD * DIM);
  float* tgt = S + MPAD;

  hipMemsetAsync(S, 0, MPAD * sizeof(float), stream);   // zero accumulators
  k_prep<<<MPAD * DIM / 2048 + N_TOK, 256, 0, stream>>>(x, W, labels, xq, tgt);
  k_gemm<<<NWG, 256, 0, stream>>>(W, xq, S);
  k_final<<<1, 256, 0, stream>>>(S, tgt, labels, out);
}

// Round 13
// 2053.447 us; speedup vs baseline: 1.0209x; 1.0209x over previous
//
#include <hip/hip_runtime.h>
#include <hip/hip_bf16.h>

// Problem constants
#define N_TOK   576
#define MPAD    640            // padded to 5*128
#define DIM     1024
#define VOCAB   262400
#define BM      128
#define BN      128
#define BK      128            // k-elements per step (fp8: 128 B rows)
#define NT      (DIM/BK)       // 8 K-steps
#define RB      5              // MPAD/BM row blocks
#define VBLKS   (VOCAB/BN)     // 2050
#define NWG     (RB*VBLKS)     // 10250
#define IGNORE_INDEX (-100)
#define SCALE1  0x7F7F7F7F     // e8m0 = 127 -> 1.0 in every byte

typedef float f32x4 __attribute__((ext_vector_type(4)));
typedef int   i32x8 __attribute__((ext_vector_type(8)));

#define AS1 __attribute__((address_space(1)))
#define AS3 __attribute__((address_space(3)))

__device__ __forceinline__ int cvt4_fp8(float4 v) {
  int r = __builtin_amdgcn_cvt_pk_fp8_f32(v.x, v.y, 0, false);   // bytes 0,1
  r     = __builtin_amdgcn_cvt_pk_fp8_f32(v.z, v.w, r, true);    // bytes 2,3
  return r;
}

// ---------- kernel 1: fused prep (x->fp8 cvt  +  exact target logits) -----
__global__ void k_prep(const float* __restrict__ x, const float* __restrict__ W,
                       const int* __restrict__ labels,
                       unsigned char* __restrict__ xq, float* __restrict__ tgt) {
  if (blockIdx.x < MPAD * DIM / 2048) {     // ---- cvt part: 320 blocks ----
    int idx = blockIdx.x * 256 + threadIdx.x;
    long e0 = (long)idx * 8;
    int row = (int)(e0 >> 10);
    uint2 o;
    if (row < N_TOK) {
      float4 a = *(const float4*)(x + e0);
      float4 b = *(const float4*)(x + e0 + 4);
      o.x = (unsigned)cvt4_fp8(a);
      o.y = (unsigned)cvt4_fp8(b);
    } else { o.x = o.y = 0u; }
    *(uint2*)(xq + e0) = o;
  } else {                                  // ---- tgt part: 576 blocks ----
    int n = blockIdx.x - MPAD * DIM / 2048;
    int lab = labels[n];
    int t = threadIdx.x;
    float s = 0.0f;
    if (lab >= 0) {
      const float4 a = ((const float4*)(x + (size_t)n * DIM))[t];
      const float4 b = ((const float4*)(W + (size_t)lab * DIM))[t];
      s = a.x*b.x + a.y*b.y + a.z*b.z + a.w*b.w;
    }
    #pragma unroll
    for (int off = 32; off >= 1; off >>= 1) s += __shfl_xor(s, off);
    __shared__ float wsum[4];
    if ((t & 63) == 0) wsum[t >> 6] = s;
    __syncthreads();
    if (t == 0) {
      float d = wsum[0] + wsum[1] + wsum[2] + wsum[3];
      tgt[n] = (lab >= 0) ? 30.0f * tanhf(d * (1.0f / 30.0f)) : 0.0f;
    }
  }
}

// ---------- kernel 2: MX-scaled fp8 GEMM (scale=1.0), spill-free ----------
// R12's verified math/layout; register-lifetime fixes ONLY:
//  (1) B is cvt'd to fp8 BEFORE barrier1 -> only ob[4] (16 VGPR) crosses
//      the barrier (R12 kept 64 VGPR of fp32 staging live -> scratch spill,
//      3.3 GB scratch writes, 4.3x slowdown).
//  (2) i32x8 frags built by static element inserts from uint4 reads (no
//      memory unions).
// Layout: BK=128 -> fp8 rows are 128B; 16B chunk j of row r at slot
// j^(r&7) (conflict-free). A via global_load_lds (linear dest, source
// pre-swizzled). MFMA: mfma_scale_f32_16x16x128_f8f6f4, scale=1.0 ==
// plain fp8 numerics at 2x rate, 4x K per inst. C/D layout shape-
// determined: col=l15, row=lh*4+j (validated: R12 absmax 0.0).
__global__ __launch_bounds__(256, 3) void k_gemm(
    const float* __restrict__ W,            // [VOCAB][DIM] fp32
    const unsigned char* __restrict__ Xq,   // [MPAD][DIM] fp8
    float* __restrict__ S)                  // [MPAD] running sum of exp(z-30)
{
  __shared__ unsigned char Asl[BM * BK];    // 16 KB
  __shared__ unsigned char Bsl[BN * BK];    // 16 KB

  // ---- bijective XCD swizzle (m204), rb-fastest logical order ----
  const int q  = NWG / 8, rm = NWG % 8;     // 1281, 2
  const int orig = blockIdx.x;
  const int xcd  = orig & 7;
  const int part = orig >> 3;
  const int bid  = (xcd < rm ? xcd * (q + 1) : rm * (q + 1) + (xcd - rm) * q) + part;

  const int rb  = bid % RB;
  const int vb  = bid / RB;
  const int m0  = rb * BM;
  const long n0 = (long)vb * BN;

  const int t   = threadIdx.x;
  const int l   = t & 63;
  const int w   = t >> 6;
  const int wm  = w >> 1, wn = w & 1;       // 2x2 waves, 64x64 per wave
  const int l15 = l & 15, lh = l >> 4;
  const int e8  = l15 & 7;

  // ---- staging geometry: 4 x 16B chunks/thread/operand ----
  const unsigned char* asrc[4];             // A source pre-swizzled
  const float* bsrc[4];                     // B source linear
  int bdst[4];                              // swizzled LDS slot
  #pragma unroll
  for (int i = 0; i < 4; ++i) {
    int lin = t + i * 256;                  // 0..1023
    int r   = lin >> 3;
    int j   = lin & 7;
    asrc[i] = Xq + (size_t)(m0 + r) * DIM + (j ^ (r & 7)) * 16;
    bsrc[i] = W + (n0 + r) * DIM + j * 16;  // 16 fp32 = one 16B fp8 chunk
    bdst[i] = r * BK + (j ^ (r & 7)) * 16;
  }
  // ---- frag read offsets: chunks {2lh, 2lh+1} swizzled ----
  const int fo0 = ((2 * lh)     ^ e8) * 16;
  const int fo1 = ((2 * lh + 1) ^ e8) * 16;

  f32x4 acc[4][4];
  const f32x4 zero4 = {0.0f, 0.0f, 0.0f, 0.0f};
  #pragma unroll
  for (int i = 0; i < 4; ++i)
    #pragma unroll
    for (int j = 0; j < 4; ++j) acc[i][j] = zero4;

  for (int k0 = 0; k0 < DIM; k0 += BK) {
    // -- B: load 4 float4 + cvt to one uint4, per chunk; fp32 temps die
    //    immediately -> only ob[4] (16 VGPR) lives across the barrier --
    uint4 ob[4];
    #pragma unroll
    for (int i = 0; i < 4; ++i) {
      float4 f0 = *(const float4*)(bsrc[i] + k0);
      float4 f1 = *(const float4*)(bsrc[i] + k0 + 4);
      float4 f2 = *(const float4*)(bsrc[i] + k0 + 8);
      float4 f3 = *(const float4*)(bsrc[i] + k0 + 12);
      ob[i].x = (unsigned)cvt4_fp8(f0);
      ob[i].y = (unsigned)cvt4_fp8(f1);
      ob[i].z = (unsigned)cvt4_fp8(f2);
      ob[i].w = (unsigned)cvt4_fp8(f3);
    }

    __syncthreads();                        // prev-iter frag reads done

    // -- A: 4 x 16B direct global->LDS (linear dest) --
    #pragma unroll
    for (int i = 0; i < 4; ++i)
      __builtin_amdgcn_global_load_lds((const AS1 void*)(asrc[i] + k0),
          (AS3 void*)(Asl + (t + i * 256) * 16), 16, 0, 0);
    // -- B: one ds_write_b128 per chunk --
    #pragma unroll
    for (int i = 0; i < 4; ++i)
      *(uint4*)(Bsl + bdst[i]) = ob[i];
    __syncthreads();                        // tiles ready (vmcnt+lgkm drained)

    // -- A frags: 4 rows x 32B, static element construction --
    i32x8 af[4];
    #pragma unroll
    for (int mi = 0; mi < 4; ++mi) {
      const unsigned char* base = Asl + (wm * 64 + mi * 16 + l15) * BK;
      uint4 x0 = *(const uint4*)(base + fo0);
      uint4 x1 = *(const uint4*)(base + fo1);
      af[mi][0] = (int)x0.x; af[mi][1] = (int)x0.y;
      af[mi][2] = (int)x0.z; af[mi][3] = (int)x0.w;
      af[mi][4] = (int)x1.x; af[mi][5] = (int)x1.y;
      af[mi][6] = (int)x1.z; af[mi][7] = (int)x1.w;
    }
    // -- B frags one at a time + 4 MFMA each --
    __builtin_amdgcn_s_setprio(1);
    #pragma unroll
    for (int ni = 0; ni < 4; ++ni) {
      const unsigned char* base = Bsl + (wn * 64 + ni * 16 + l15) * BK;
      uint4 y0 = *(const uint4*)(base + fo0);
      uint4 y1 = *(const uint4*)(base + fo1);
      i32x8 bf;
      bf[0] = (int)y0.x; bf[1] = (int)y0.y; bf[2] = (int)y0.z; bf[3] = (int)y0.w;
      bf[4] = (int)y1.x; bf[5] = (int)y1.y; bf[6] = (int)y1.z; bf[7] = (int)y1.w;
      #pragma unroll
      for (int mi = 0; mi < 4; ++mi)
        acc[mi][ni] = __builtin_amdgcn_mfma_scale_f32_16x16x128_f8f6f4(
            af[mi], bf, acc[mi][ni],
            0, 0,                           // cbsz=fp8, blgp=fp8
            0, SCALE1,                      // opsel_a, scale_a = 1.0
            0, SCALE1);                     // opsel_b, scale_b = 1.0
    }
    __builtin_amdgcn_s_setprio(0);
  }

  // ---- epilogue: p = exp(z-30) = exp(-60/(exp(g/15)+1)); row sums; atomics
  // C frag layout (validated R12): col = l15 (vocab), row = lh*4 + j
  #pragma unroll
  for (int mi = 0; mi < 4; ++mi) {
    #pragma unroll
    for (int j = 0; j < 4; ++j) {
      float s = 0.0f;
      #pragma unroll
      for (int ni = 0; ni < 4; ++ni) {
        float g   = acc[mi][ni][j];
        float tp1 = __expf(g * (1.0f / 15.0f)) + 1.0f;
        s += __expf(-60.0f * __builtin_amdgcn_rcpf(tp1));
      }
      s += __shfl_xor(s, 1);
      s += __shfl_xor(s, 2);
      s += __shfl_xor(s, 4);
      s += __shfl_xor(s, 8);
      if (l15 == 0) {
        int row = m0 + wm * 64 + mi * 16 + lh * 4 + j;
        atomicAdd(&S[row], s);              // padded rows land in S[576..640)
      }
    }
  }
}

// ---------- kernel 3: final reduce -> loss ----------
__global__ void k_final(const float* __restrict__ S, const float* __restrict__ tgt,
                        const int* __restrict__ labels, float* __restrict__ out) {
  int t = threadIdx.x;
  float sum = 0.0f, cnt = 0.0f;
  for (int n = t; n < N_TOK; n += 256) {
    if (labels[n] != IGNORE_INDEX) {
      sum += 30.0f + __logf(S[n]) - tgt[n];  // lse = 30 + log(sum exp(z-30))
      cnt += 1.0f;
    }
  }
  #pragma unroll
  for (int off = 32; off >= 1; off >>= 1) {
    sum += __shfl_xor(sum, off);
    cnt += __shfl_xor(cnt, off);
  }
  __shared__ float as_[4], ac_[4];
  if ((t & 63) == 0) { as_[t >> 6] = sum; ac_[t >> 6] = cnt; }
  __syncthreads();
  if (t == 0) out[0] = (as_[0]+as_[1]+as_[2]+as_[3]) / (ac_[0]+ac_[1]+ac_[2]+ac_[3]);
}

extern "C" void kernel_launch(void* const* d_in, const int* in_sizes, int n_in,
                              void* d_out, int out_size, void* d_ws, size_t ws_size,
                              hipStream_t stream) {
  const float* x      = (const float*)d_in[0];
  const float* W      = (const float*)d_in[1];
  const int*   labels = (const int*)d_in[2];
  float* out = (float*)d_out;

  // ws layout: xq [640*1024 fp8] | S [640 f32] | tgt [576 f32]  (~0.66 MB)
  char* ws = (char*)d_ws;
  unsigned char* xq = (unsigned char*)ws;
  float* S   = (float*)(ws + (size_t)MPAD * DIM);
  float* tgt = S + MPAD;

  hipMemsetAsync(S, 0, MPAD * sizeof(float), stream);   // zero accumulators
  k_prep<<<MPAD * DIM / 2048 + N_TOK, 256, 0, stream>>>(x, W, labels, xq, tgt);
  k_gemm<<<NWG, 256, 0, stream>>>(W, xq, S);
  k_final<<<1, 256, 0, stream>>>(S, tgt, labels, out);
}

// Round 14
// 845.042 us; speedup vs baseline: 2.4808x; 2.4300x over previous
//
#include <hip/hip_runtime.h>
#include <hip/hip_bf16.h>

// Problem constants
#define N_TOK   576
#define MPAD    640            // padded to 5*128
#define DIM     1024
#define VOCAB   262400
#define BM      128
#define BN      64             // smaller N-tile -> acc 32 -> 20 waves/CU
#define BK      64             // k-elements per step (fp8: 64 B rows)
#define RB      5              // MPAD/BM row blocks
#define VBLKS   (VOCAB/BN)     // 4100
#define NWG     (RB*VBLKS)     // 20500
#define IGNORE_INDEX (-100)

typedef float f32x4 __attribute__((ext_vector_type(4)));

#define AS1 __attribute__((address_space(1)))
#define AS3 __attribute__((address_space(3)))

__device__ __forceinline__ int cvt4_fp8(float4 v) {
  int r = __builtin_amdgcn_cvt_pk_fp8_f32(v.x, v.y, 0, false);   // bytes 0,1
  r     = __builtin_amdgcn_cvt_pk_fp8_f32(v.z, v.w, r, true);    // bytes 2,3
  return r;
}

// ---------- kernel 1: fused prep (x->fp8 cvt  +  exact target logits) -----
__global__ void k_prep(const float* __restrict__ x, const float* __restrict__ W,
                       const int* __restrict__ labels,
                       unsigned char* __restrict__ xq, float* __restrict__ tgt) {
  if (blockIdx.x < MPAD * DIM / 2048) {     // ---- cvt part: 320 blocks ----
    int idx = blockIdx.x * 256 + threadIdx.x;
    long e0 = (long)idx * 8;
    int row = (int)(e0 >> 10);
    uint2 o;
    if (row < N_TOK) {
      float4 a = *(const float4*)(x + e0);
      float4 b = *(const float4*)(x + e0 + 4);
      o.x = (unsigned)cvt4_fp8(a);
      o.y = (unsigned)cvt4_fp8(b);
    } else { o.x = o.y = 0u; }
    *(uint2*)(xq + e0) = o;
  } else {                                  // ---- tgt part: 576 blocks ----
    int n = blockIdx.x - MPAD * DIM / 2048;
    int lab = labels[n];
    int t = threadIdx.x;
    float s = 0.0f;
    if (lab >= 0) {
      const float4 a = ((const float4*)(x + (size_t)n * DIM))[t];
      const float4 b = ((const float4*)(W + (size_t)lab * DIM))[t];
      s = a.x*b.x + a.y*b.y + a.z*b.z + a.w*b.w;
    }
    #pragma unroll
    for (int off = 32; off >= 1; off >>= 1) s += __shfl_xor(s, off);
    __shared__ float wsum[4];
    if ((t & 63) == 0) wsum[t >> 6] = s;
    __syncthreads();
    if (t == 0) {
      float d = wsum[0] + wsum[1] + wsum[2] + wsum[3];
      tgt[n] = (lab >= 0) ? 30.0f * tanhf(d * (1.0f / 30.0f)) : 0.0f;
    }
  }
}

// ---------- kernel 2: fp8 GEMM, R9 layout, 128x64 tile, 20 waves/CU -------
// R9's proven paired-row fp8 LDS layout + 2-barrier loop; wave tile 64x32
// (acc 32 AGPR instead of 64) -> ~96 regs/thread -> 5 blocks/CU (20 waves,
// +25% TLP vs R9's VGPR-capped 16). A staging unchanged (128 rows). B tile
// 64 rows (4 KB). Trades +33% A-frag LDS traffic (pipe at ~35%) and +20%
// L2/FLOP (at ~42%) for latency hiding -- the only unexplored axis after
// R3/R4/R5/R6/R10/R11 scheduling attempts all came back null.
__global__ __launch_bounds__(256, 5) void k_gemm(
    const float* __restrict__ W,            // [VOCAB][DIM] fp32
    const unsigned char* __restrict__ Xq,   // [MPAD][DIM] fp8
    float* __restrict__ S)                  // [MPAD] running sum of exp(z-30)
{
  __shared__ unsigned char Asl[BM * BK];    // 8 KB (64 pair-lines x 128 B)
  __shared__ unsigned char Bsl[BN * BK];    // 4 KB (32 pair-lines x 128 B)

  // ---- bijective XCD swizzle (m204), rb-fastest logical order ----
  const int q  = NWG / 8, rm = NWG % 8;     // 2562, 4
  const int orig = blockIdx.x;
  const int xcd  = orig & 7;
  const int part = orig >> 3;
  const int bid  = (xcd < rm ? xcd * (q + 1) : rm * (q + 1) + (xcd - rm) * q) + part;

  const int rb  = bid % RB;
  const int vb  = bid / RB;
  const int m0  = rb * BM;
  const long n0 = (long)vb * BN;

  const int t   = threadIdx.x;
  const int l   = t & 63;
  const int w   = t >> 6;
  const int wm  = w >> 1, wn = w & 1;       // 2x2 waves, wave tile 64M x 32N
  const int l15 = l & 15, lh = l >> 4;

  // ---- A staging: gload_lds linear dest, inverse-swizzled source (R9) ----
  const unsigned char* asrc[2];
  #pragma unroll
  for (int i = 0; i < 2; ++i) {
    int lin = t + i * 256;                  // 0..511
    int p   = lin >> 3;
    int c   = (lin & 7) ^ (p & 7);
    asrc[i] = Xq + (size_t)(m0 + 2 * p + (c >> 2)) * DIM + (c & 3) * 16;
  }
  // ---- B staging: 2 x (8 floats -> 8 fp8 at swizzled 8B slot) ----
  const float* bsrc[2];
  int boff[2];
  #pragma unroll
  for (int i = 0; i < 2; ++i) {
    int lin = t + i * 256;                  // 0..511
    int r   = lin >> 3;                     // row 0..63
    int g   = lin & 7;
    bsrc[i] = W + (n0 + r) * DIM + g * 8;
    int p = r >> 1, s = r & 1;
    int jj = g >> 1, hb = g & 1;
    boff[i] = p * 128 + ((((s << 2) | jj) ^ (p & 7)) << 4) + (hb << 3);
  }
  // ---- frag read offsets (paired-row swizzle, R9) ----
  const int pr = l15 >> 1, sr = l15 & 1;
  int fo[2];
  #pragma unroll
  for (int kk = 0; kk < 2; ++kk)
    fo[kk] = pr * 128 + (((((sr << 2) | (kk * 2 + (lh >> 1))) ^ pr)) << 4)
           + ((lh & 1) << 3);
  const int abase = wm * 4096;              // wm*64 rows = wm*32 pair-lines
  const int bbase = wn * 2048;              // wn*32 rows = wn*16 pair-lines

  f32x4 acc[4][2];
  const f32x4 zero4 = {0.0f, 0.0f, 0.0f, 0.0f};
  #pragma unroll
  for (int i = 0; i < 4; ++i)
    #pragma unroll
    for (int j = 0; j < 2; ++j) acc[i][j] = zero4;

  for (int k0 = 0; k0 < DIM; k0 += BK) {
    // -- B global loads issued BEFORE the barrier (hide under prev MFMA) --
    float4 fb[2][2];
    #pragma unroll
    for (int i = 0; i < 2; ++i) {
      fb[i][0] = *(const float4*)(bsrc[i] + k0);
      fb[i][1] = *(const float4*)(bsrc[i] + k0 + 4);
    }
    __syncthreads();                        // prev-iter frag reads done
    // -- A: 2 x 16B direct global->LDS --
    #pragma unroll
    for (int i = 0; i < 2; ++i)
      __builtin_amdgcn_global_load_lds((const AS1 void*)(asrc[i] + k0),
          (AS3 void*)(Asl + (t + i * 256) * 16), 16, 0, 0);
    // -- B: cvt fp32->fp8, swizzled 8B writes --
    #pragma unroll
    for (int i = 0; i < 2; ++i) {
      int lo = cvt4_fp8(fb[i][0]);
      int hi = cvt4_fp8(fb[i][1]);
      *(int2*)(Bsl + boff[i]) = make_int2(lo, hi);
    }
    __syncthreads();                        // tiles ready

    // -- fragments (ds_read_b64, conflict-free) + MFMA --
    long af[4][2], bf[2][2];
    #pragma unroll
    for (int mi = 0; mi < 4; ++mi) {
      af[mi][0] = *(const long*)(Asl + abase + mi * 1024 + fo[0]);
      af[mi][1] = *(const long*)(Asl + abase + mi * 1024 + fo[1]);
    }
    #pragma unroll
    for (int ni = 0; ni < 2; ++ni) {
      bf[ni][0] = *(const long*)(Bsl + bbase + ni * 1024 + fo[0]);
      bf[ni][1] = *(const long*)(Bsl + bbase + ni * 1024 + fo[1]);
    }
    __builtin_amdgcn_s_setprio(1);
    #pragma unroll
    for (int kk = 0; kk < 2; ++kk)
      #pragma unroll
      for (int mi = 0; mi < 4; ++mi)
        #pragma unroll
        for (int ni = 0; ni < 2; ++ni)
          acc[mi][ni] = __builtin_amdgcn_mfma_f32_16x16x32_fp8_fp8(
              af[mi][kk], bf[ni][kk], acc[mi][ni], 0, 0, 0);
    __builtin_amdgcn_s_setprio(0);
  }

  // ---- epilogue: p = exp(z-30) = exp(-60/(exp(g/15)+1)); row sums; atomics
  // C frag layout (HW-validated R7-R11): col = l15, row = lh*4 + j
  #pragma unroll
  for (int mi = 0; mi < 4; ++mi) {
    #pragma unroll
    for (int j = 0; j < 4; ++j) {
      float s = 0.0f;
      #pragma unroll
      for (int ni = 0; ni < 2; ++ni) {
        float g   = acc[mi][ni][j];
        float tp1 = __expf(g * (1.0f / 15.0f)) + 1.0f;
        s += __expf(-60.0f * __builtin_amdgcn_rcpf(tp1));
      }
      s += __shfl_xor(s, 1);
      s += __shfl_xor(s, 2);
      s += __shfl_xor(s, 4);
      s += __shfl_xor(s, 8);
      if (l15 == 0) {
        int row = m0 + wm * 64 + mi * 16 + lh * 4 + j;
        atomicAdd(&S[row], s);              // padded rows land in S[576..640)
      }
    }
  }
}

// ---------- kernel 3: final reduce -> loss ----------
__global__ void k_final(const float* __restrict__ S, const float* __restrict__ tgt,
                        const int* __restrict__ labels, float* __restrict__ out) {
  int t = threadIdx.x;
  float sum = 0.0f, cnt = 0.0f;
  for (int n = t; n < N_TOK; n += 256) {
    if (labels[n] != IGNORE_INDEX) {
      sum += 30.0f + __logf(S[n]) - tgt[n];  // lse = 30 + log(sum exp(z-30))
      cnt += 1.0f;
    }
  }
  #pragma unroll
  for (int off = 32; off >= 1; off >>= 1) {
    sum += __shfl_xor(sum, off);
    cnt += __shfl_xor(cnt, off);
  }
  __shared__ float as_[4], ac_[4];
  if ((t & 63) == 0) { as_[t >> 6] = sum; ac_[t >> 6] = cnt; }
  __syncthreads();
  if (t == 0) out[0] = (as_[0]+as_[1]+as_[2]+as_[3]) / (ac_[0]+ac_[1]+ac_[2]+ac_[3]);
}

extern "C" void kernel_launch(void* const* d_in, const int* in_sizes, int n_in,
                              void* d_out, int out_size, void* d_ws, size_t ws_size,
                              hipStream_t stream) {
  const float* x      = (const float*)d_in[0];
  const float* W      = (const float*)d_in[1];
  const int*   labels = (const int*)d_in[2];
  float* out = (float*)d_out;

  // ws layout: xq [640*1024 fp8] | S [640 f32] | tgt [576 f32]  (~0.66 MB)
  char* ws = (char*)d_ws;
  unsigned char* xq = (unsigned char*)ws;
  float* S   = (float*)(ws + (size_t)MPAD * DIM);
  float* tgt = S + MPAD;

  hipMemsetAsync(S, 0, MPAD * sizeof(float), stream);   // zero accumulators
  k_prep<<<MPAD * DIM / 2048 + N_TOK, 256, 0, stream>>>(x, W, labels, xq, tgt);
  k_gemm<<<NWG, 256, 0, stream>>>(W, xq, S);
  k_final<<<1, 256, 0, stream>>>(S, tgt, labels, out);
}

// Round 15
// 551.229 us; speedup vs baseline: 3.8031x; 1.5330x over previous
//
#include <hip/hip_runtime.h>
#include <hip/hip_bf16.h>

// Problem constants
#define N_TOK   576
#define MPAD    640            // padded to 5*128
#define DIM     1024
#define VOCAB   262400
#define BM      128
#define BN      128
#define BK      64             // k-elements per step (fp8: 64 B rows)
#define RB      5              // MPAD/BM row blocks
#define VBLKS   (VOCAB/BN)     // 2050
#define NWG     (RB*VBLKS)     // 10250
#define IGNORE_INDEX (-100)

typedef float f32x4 __attribute__((ext_vector_type(4)));

__device__ __forceinline__ int cvt4_fp8(float4 v) {
  int r = __builtin_amdgcn_cvt_pk_fp8_f32(v.x, v.y, 0, false);   // bytes 0,1
  r     = __builtin_amdgcn_cvt_pk_fp8_f32(v.z, v.w, r, true);    // bytes 2,3
  return r;
}

// Raw barrier: orders LDS ops only. No vmcnt drain -- global loads stay in
// flight across it; the compiler's counted vmcnt waits them at the consumer.
// Safe here: k_gemm contains NO global_load_lds (A is reg-staged).
#define BARRIER() do {                                          \
    asm volatile("s_waitcnt lgkmcnt(0)" ::: "memory");          \
    __builtin_amdgcn_s_barrier();                               \
    __builtin_amdgcn_sched_barrier(0);                          \
  } while (0)

// ---------- kernel 1: fused prep (x->fp8 cvt  +  exact target logits) -----
__global__ void k_prep(const float* __restrict__ x, const float* __restrict__ W,
                       const int* __restrict__ labels,
                       unsigned char* __restrict__ xq, float* __restrict__ tgt) {
  if (blockIdx.x < MPAD * DIM / 2048) {     // ---- cvt part: 320 blocks ----
    int idx = blockIdx.x * 256 + threadIdx.x;
    long e0 = (long)idx * 8;
    int row = (int)(e0 >> 10);
    uint2 o;
    if (row < N_TOK) {
      float4 a = *(const float4*)(x + e0);
      float4 b = *(const float4*)(x + e0 + 4);
      o.x = (unsigned)cvt4_fp8(a);
      o.y = (unsigned)cvt4_fp8(b);
    } else { o.x = o.y = 0u; }
    *(uint2*)(xq + e0) = o;
  } else {                                  // ---- tgt part: 576 blocks ----
    int n = blockIdx.x - MPAD * DIM / 2048;
    int lab = labels[n];
    int t = threadIdx.x;
    float s = 0.0f;
    if (lab >= 0) {
      const float4 a = ((const float4*)(x + (size_t)n * DIM))[t];
      const float4 b = ((const float4*)(W + (size_t)lab * DIM))[t];
      s = a.x*b.x + a.y*b.y + a.z*b.z + a.w*b.w;
    }
    #pragma unroll
    for (int off = 32; off >= 1; off >>= 1) s += __shfl_xor(s, off);
    __shared__ float wsum[4];
    if ((t & 63) == 0) wsum[t >> 6] = s;
    __syncthreads();
    if (t == 0) {
      float d = wsum[0] + wsum[1] + wsum[2] + wsum[3];
      tgt[n] = (lab >= 0) ? 30.0f * tanhf(d * (1.0f / 30.0f)) : 0.0f;
    }
  }
}

// ---------- kernel 2: fp8 GEMM, phase-conflict-free granule swizzle -------
// R9 geometry (128x128x64, 4 waves 2x2, wave tile 64x64). LDS layout:
// two 64B fp8 rows share a 128B line (pair p = row>>1, parity s = row&1);
// 8B granule k8 of row r stored at granule g = s*8 + (k8 ^ (p&7)).
// Phase analysis (b64 ops service 16 lanes/phase, 2 banks/lane): within any
// phase the 16 g values are distinct -> all 32 banks covered once -> ZERO
// conflicts on frag reads, A writes, and B writes. (R9's layout kept lh&1
// as the half-bit -- constant per phase -> 2-way conflicts, 6.3e7 cycles
// measured in R7/R14. This map moves the half-bit to s.)
// The half-swap for odd p is inexpressible by global_load_lds -> A is
// REG-staged (2x16B load + 4x ds_write_b64; Xq is L2-resident). With no
// gload_lds, barriers are raw s_barrier + lgkmcnt(0): NO block-wide
// vmcnt(0) drain -- W/A loads fly across barrier1 into the cvt's counted
// per-wave wait.
__global__ __launch_bounds__(256, 4) void k_gemm(
    const float* __restrict__ W,            // [VOCAB][DIM] fp32
    const unsigned char* __restrict__ Xq,   // [MPAD][DIM] fp8
    float* __restrict__ S)                  // [MPAD] running sum of exp(z-30)
{
  __shared__ unsigned char Asl[BM * BK];    // 8 KB (64 lines x 128 B)
  __shared__ unsigned char Bsl[BN * BK];    // 8 KB

  // ---- bijective XCD swizzle (m204), rb-fastest logical order ----
  const int q  = NWG / 8, rm = NWG % 8;     // 1281, 2
  const int orig = blockIdx.x;
  const int xcd  = orig & 7;
  const int part = orig >> 3;
  const int bid  = (xcd < rm ? xcd * (q + 1) : rm * (q + 1) + (xcd - rm) * q) + part;

  const int rb  = bid % RB;
  const int vb  = bid / RB;
  const int m0  = rb * BM;
  const long n0 = (long)vb * BN;

  const int t   = threadIdx.x;
  const int l   = t & 63;
  const int w   = t >> 6;
  const int wm  = w >> 1, wn = w & 1;       // 2x2 waves, 64x64 per wave
  const int l15 = l & 15, lh = l >> 4;

  // ---- A staging (reg): 2 x 16B chunks -> 2+2 swizzled b64 writes ----
  // lin = t + i*256 (0..511): r = lin>>2 (row), c16 = lin&3 (16B chunk).
  const unsigned char* asrc[2];
  int aoff0[2], aoff1[2];
  #pragma unroll
  for (int i = 0; i < 2; ++i) {
    int lin = t + i * 256;
    int r   = lin >> 2;
    int c16 = lin & 3;
    asrc[i] = Xq + (size_t)(m0 + r) * DIM + c16 * 16;
    int p = r >> 1, s = r & 1, pp = p & 7;
    aoff0[i] = p * 128 + (s * 8 + ((2 * c16)     ^ pp)) * 8;
    aoff1[i] = p * 128 + (s * 8 + ((2 * c16 + 1) ^ pp)) * 8;
  }
  // ---- B staging: 4 x (8 floats -> 8 fp8 granule) swizzled writes ----
  // lin = t + i*256 (0..1023): r = lin>>3, k8 = lin&7.
  const float* bsrc[4];
  int boff[4];
  #pragma unroll
  for (int i = 0; i < 4; ++i) {
    int lin = t + i * 256;
    int r   = lin >> 3;
    int k8  = lin & 7;
    bsrc[i] = W + (n0 + r) * DIM + k8 * 8;
    int p = r >> 1, s = r & 1;
    boff[i] = p * 128 + (s * 8 + (k8 ^ (p & 7))) * 8;
  }
  // ---- frag read offsets: row = base + l15 -> p&7 = l15>>1, s = l15&1;
  //      k8 = kk*4 + lh;  g = s*8 + (k8 ^ pr) ----
  const int pr = l15 >> 1, sr = l15 & 1;
  int fo[2];
  #pragma unroll
  for (int kk = 0; kk < 2; ++kk)
    fo[kk] = pr * 128 + sr * 64 + (((kk * 4 + lh) ^ pr)) * 8;
  const int abase = wm * 4096;              // wm*64 rows = wm*32 lines
  const int bbase = wn * 4096;

  f32x4 acc[4][4];
  const f32x4 zero4 = {0.0f, 0.0f, 0.0f, 0.0f};
  #pragma unroll
  for (int i = 0; i < 4; ++i)
    #pragma unroll
    for (int j = 0; j < 4; ++j) acc[i][j] = zero4;

  for (int k0 = 0; k0 < DIM; k0 += BK) {
    // -- issue all global loads (they fly across BARRIER1, waited at cvt) --
    float4 fb[4][2];
    #pragma unroll
    for (int i = 0; i < 4; ++i) {
      fb[i][0] = *(const float4*)(bsrc[i] + k0);
      fb[i][1] = *(const float4*)(bsrc[i] + k0 + 4);
    }
    uint4 ua[2];
    #pragma unroll
    for (int i = 0; i < 2; ++i)
      ua[i] = *(const uint4*)(asrc[i] + k0);

    BARRIER();                              // prev-iter frag reads done (lgkm)

    // -- A: 4 x b64 swizzled writes (halves split per granule map) --
    #pragma unroll
    for (int i = 0; i < 2; ++i) {
      *(uint2*)(Asl + aoff0[i]) = make_uint2(ua[i].x, ua[i].y);
      *(uint2*)(Asl + aoff1[i]) = make_uint2(ua[i].z, ua[i].w);
    }
    // -- B: cvt fp32->fp8, 4 x b64 swizzled writes --
    #pragma unroll
    for (int i = 0; i < 4; ++i) {
      int lo = cvt4_fp8(fb[i][0]);
      int hi = cvt4_fp8(fb[i][1]);
      *(int2*)(Bsl + boff[i]) = make_int2(lo, hi);
    }
    BARRIER();                              // tiles published (lgkm only)

    // -- fragments (ds_read_b64, zero-conflict) + MFMA --
    long af[4][2], bf[4][2];
    #pragma unroll
    for (int mi = 0; mi < 4; ++mi) {
      af[mi][0] = *(const long*)(Asl + abase + mi * 1024 + fo[0]);
      af[mi][1] = *(const long*)(Asl + abase + mi * 1024 + fo[1]);
    }
    #pragma unroll
    for (int ni = 0; ni < 4; ++ni) {
      bf[ni][0] = *(const long*)(Bsl + bbase + ni * 1024 + fo[0]);
      bf[ni][1] = *(const long*)(Bsl + bbase + ni * 1024 + fo[1]);
    }
    __builtin_amdgcn_s_setprio(1);
    #pragma unroll
    for (int kk = 0; kk < 2; ++kk)
      #pragma unroll
      for (int mi = 0; mi < 4; ++mi)
        #pragma unroll
        for (int ni = 0; ni < 4; ++ni)
          acc[mi][ni] = __builtin_amdgcn_mfma_f32_16x16x32_fp8_fp8(
              af[mi][kk], bf[ni][kk], acc[mi][ni], 0, 0, 0);
    __builtin_amdgcn_s_setprio(0);
  }

  // ---- epilogue: p = exp(z-30) = exp(-60/(exp(g/15)+1)); row sums; atomics
  // C frag layout (HW-validated R7-R14): col = l15, row = lh*4 + j
  #pragma unroll
  for (int mi = 0; mi < 4; ++mi) {
    #pragma unroll
    for (int j = 0; j < 4; ++j) {
      float s = 0.0f;
      #pragma unroll
      for (int ni = 0; ni < 4; ++ni) {
        float g   = acc[mi][ni][j];
        float tp1 = __expf(g * (1.0f / 15.0f)) + 1.0f;
        s += __expf(-60.0f * __builtin_amdgcn_rcpf(tp1));
      }
      s += __shfl_xor(s, 1);
      s += __shfl_xor(s, 2);
      s += __shfl_xor(s, 4);
      s += __shfl_xor(s, 8);
      if (l15 == 0) {
        int row = m0 + wm * 64 + mi * 16 + lh * 4 + j;
        atomicAdd(&S[row], s);              // padded rows land in S[576..640)
      }
    }
  }
}

// ---------- kernel 3: final reduce -> loss ----------
__global__ void k_final(const float* __restrict__ S, const float* __restrict__ tgt,
                        const int* __restrict__ labels, float* __restrict__ out) {
  int t = threadIdx.x;
  float sum = 0.0f, cnt = 0.0f;
  for (int n = t; n < N_TOK; n += 256) {
    if (labels[n] != IGNORE_INDEX) {
      sum += 30.0f + __logf(S[n]) - tgt[n];  // lse = 30 + log(sum exp(z-30))
      cnt += 1.0f;
    }
  }
  #pragma unroll
  for (int off = 32; off >= 1; off >>= 1) {
    sum += __shfl_xor(sum, off);
    cnt += __shfl_xor(cnt, off);
  }
  __shared__ float as_[4], ac_[4];
  if ((t & 63) == 0) { as_[t >> 6] = sum; ac_[t >> 6] = cnt; }
  __syncthreads();
  if (t == 0) out[0] = (as_[0]+as_[1]+as_[2]+as_[3]) / (ac_[0]+ac_[1]+ac_[2]+ac_[3]);
}

extern "C" void kernel_launch(void* const* d_in, const int* in_sizes, int n_in,
                              void* d_out, int out_size, void* d_ws, size_t ws_size,
                              hipStream_t stream) {
  const float* x      = (const float*)d_in[0];
  const float* W      = (const float*)d_in[1];
  const int*   labels = (const int*)d_in[2];
  float* out = (float*)d_out;

  // ws layout: xq [640*1024 fp8] | S [640 f32] | tgt [576 f32]  (~0.66 MB)
  char* ws = (char*)d_ws;
  unsigned char* xq = (unsigned char*)ws;
  float* S   = (float*)(ws + (size_t)MPAD * DIM);
  float* tgt = S + MPAD;

  hipMemsetAsync(S, 0, MPAD * sizeof(float), stream);   // zero accumulators
  k_prep<<<MPAD * DIM / 2048 + N_TOK, 256, 0, stream>>>(x, W, labels, xq, tgt);
  k_gemm<<<NWG, 256, 0, stream>>>(W, xq, S);
  k_final<<<1, 256, 0, stream>>>(S, tgt, labels, out);
}